// Round 1
// baseline (1779.300 us; speedup 1.0000x reference)
//
#include <hip/hip_runtime.h>

#define N_NODES 100000
#define N_EDGES 1600000
#define DIM 128
#define NCLS 64
#define NG 128
#define BN_EPS 1e-5f

// ---------------- degree histogram ----------------
__global__ void k_hist(const int* __restrict__ dst, int* __restrict__ cnt) {
    int e = blockIdx.x * 256 + threadIdx.x;
    if (e < N_EDGES) atomicAdd(&cnt[dst[e]], 1);
}

// ---------------- exclusive scan (3 kernels) ----------------
__global__ void k_scan1(const int* __restrict__ cnt, int* __restrict__ rowptr,
                        int* __restrict__ bsums) {
    __shared__ int sd[1024];
    int tid = threadIdx.x;
    int i = blockIdx.x * 1024 + tid;
    int v = (i < N_NODES) ? cnt[i] : 0;
    sd[tid] = v;
    __syncthreads();
    for (int off = 1; off < 1024; off <<= 1) {
        int t2 = (tid >= off) ? sd[tid - off] : 0;
        __syncthreads();
        sd[tid] += t2;
        __syncthreads();
    }
    if (i < N_NODES) rowptr[i] = sd[tid] - v;   // exclusive within block
    if (tid == 1023) bsums[blockIdx.x] = sd[tid];
}

__global__ void k_scan2(int* bsums, int nb) {
    if (threadIdx.x == 0) {
        int run = 0;
        for (int b = 0; b < nb; ++b) { int v = bsums[b]; bsums[b] = run; run += v; }
    }
}

__global__ void k_scan3(int* __restrict__ rowptr, const int* __restrict__ bsums,
                        int* __restrict__ wcur) {
    int i = blockIdx.x * 1024 + threadIdx.x;
    if (i < N_NODES) {
        int v = rowptr[i] + bsums[blockIdx.x];
        rowptr[i] = v;
        wcur[i] = v;
    }
    if (i == N_NODES - 1) rowptr[N_NODES] = N_EDGES;
}

// ---------------- bucket edges by dst ----------------
__global__ void k_scatter(const int* __restrict__ src, const int* __restrict__ dst,
                          int* __restrict__ wcur, int2* __restrict__ esort) {
    int e = blockIdx.x * 256 + threadIdx.x;
    if (e < N_EDGES) {
        int d = dst[e];
        int p = atomicAdd(&wcur[d], 1);
        esort[p] = make_int2(e, src[e]);
    }
}

// ---------------- gather-aggregate: one wave per node ----------------
__global__ void k_agg(const float* __restrict__ F, const float* __restrict__ xe,
                      const int* __restrict__ rowptr, const int2* __restrict__ esort,
                      float* __restrict__ agg) {
    int wid = (blockIdx.x * blockDim.x + threadIdx.x) >> 6;  // node id
    int lane = threadIdx.x & 63;
    if (wid >= N_NODES) return;
    int p0 = rowptr[wid], p1 = rowptr[wid + 1];
    float accx = 0.f, accy = 0.f;
    for (int p = p0; p < p1; ++p) {
        int2 es = esort[p];
        float2 a = *reinterpret_cast<const float2*>(&F[(size_t)es.y * DIM + lane * 2]);
        float2 b = *reinterpret_cast<const float2*>(&xe[(size_t)es.x * DIM + lane * 2]);
        accx += fmaxf(a.x + b.x, 0.f);
        accy += fmaxf(a.y + b.y, 0.f);
    }
    float s = 1.f / (float)max(p1 - p0, 1);
    float2 o; o.x = accx * s; o.y = accy * s;
    *reinterpret_cast<float2*>(&agg[(size_t)wid * DIM + lane * 2]) = o;
}

// ---------------- fused dual GEMM: OUT = A@W1^T + B@W2^T + bias (+BN stats) ----
__global__ __launch_bounds__(256, 2) void k_gemm2(
        const float* __restrict__ A, const float* __restrict__ B,
        const float* __restrict__ W1, const float* __restrict__ W2,
        const float* __restrict__ bias, float* __restrict__ OUT,
        float* __restrict__ bnacc, int doBN) {
    __shared__ float As[64][36];
    __shared__ float Bs[64][36];
    __shared__ float W1s[128][36];
    __shared__ float W2s[128][36];
    int t = threadIdx.x;
    int n0 = blockIdx.x * 64;
    int tn = t >> 4;   // 0..15  node group (4 nodes each)
    int td = t & 15;   // 0..15  dim group  (dims d = td + 16*j)
    float acc[4][8];
#pragma unroll
    for (int i = 0; i < 4; ++i)
#pragma unroll
        for (int j = 0; j < 8; ++j) acc[i][j] = 0.f;

    int lr = t >> 3;          // 0..31
    int lc = (t & 7) * 4;     // 0..28

    for (int kc = 0; kc < 4; ++kc) {
        int kb = kc * 32;
        __syncthreads();
#pragma unroll
        for (int h = 0; h < 2; ++h) {
            int r = lr + h * 32;
            int n = n0 + r; if (n > N_NODES - 1) n = N_NODES - 1;
            *reinterpret_cast<float4*>(&As[r][lc]) =
                *reinterpret_cast<const float4*>(&A[(size_t)n * DIM + kb + lc]);
            *reinterpret_cast<float4*>(&Bs[r][lc]) =
                *reinterpret_cast<const float4*>(&B[(size_t)n * DIM + kb + lc]);
        }
#pragma unroll
        for (int h = 0; h < 4; ++h) {
            int r = lr + h * 32;
            *reinterpret_cast<float4*>(&W1s[r][lc]) =
                *reinterpret_cast<const float4*>(&W1[(size_t)r * DIM + kb + lc]);
            *reinterpret_cast<float4*>(&W2s[r][lc]) =
                *reinterpret_cast<const float4*>(&W2[(size_t)r * DIM + kb + lc]);
        }
        __syncthreads();
#pragma unroll
        for (int kk = 0; kk < 8; ++kk) {
            float4 a[4], b[4], w1[8], w2[8];
#pragma unroll
            for (int i = 0; i < 4; ++i) {
                a[i] = *reinterpret_cast<const float4*>(&As[tn * 4 + i][kk * 4]);
                b[i] = *reinterpret_cast<const float4*>(&Bs[tn * 4 + i][kk * 4]);
            }
#pragma unroll
            for (int j = 0; j < 8; ++j) {
                w1[j] = *reinterpret_cast<const float4*>(&W1s[td + 16 * j][kk * 4]);
                w2[j] = *reinterpret_cast<const float4*>(&W2s[td + 16 * j][kk * 4]);
            }
#pragma unroll
            for (int i = 0; i < 4; ++i)
#pragma unroll
                for (int j = 0; j < 8; ++j) {
                    acc[i][j] += a[i].x * w1[j].x + a[i].y * w1[j].y
                               + a[i].z * w1[j].z + a[i].w * w1[j].w
                               + b[i].x * w2[j].x + b[i].y * w2[j].y
                               + b[i].z * w2[j].z + b[i].w * w2[j].w;
                }
        }
    }

    float bj[8];
#pragma unroll
    for (int j = 0; j < 8; ++j) bj[j] = bias[td + 16 * j];
    float p1s[8], p2s[8];
#pragma unroll
    for (int j = 0; j < 8; ++j) { p1s[j] = 0.f; p2s[j] = 0.f; }
#pragma unroll
    for (int i = 0; i < 4; ++i) {
        int n = n0 + tn * 4 + i;
        if (n < N_NODES) {
#pragma unroll
            for (int j = 0; j < 8; ++j) {
                float h = acc[i][j] + bj[j];
                OUT[(size_t)n * DIM + td + 16 * j] = h;
                p1s[j] += h;
                p2s[j] += h * h;
            }
        }
    }
    if (doBN) {
        __syncthreads();
        float* red1 = &As[0][0];   // 16*128 = 2048 <= 2304 floats
        float* red2 = &Bs[0][0];
#pragma unroll
        for (int j = 0; j < 8; ++j) {
            red1[tn * 128 + td + 16 * j] = p1s[j];
            red2[tn * 128 + td + 16 * j] = p2s[j];
        }
        __syncthreads();
        if (t < 128) {
            float s1 = 0.f, s2 = 0.f;
#pragma unroll
            for (int g = 0; g < 16; ++g) { s1 += red1[g * 128 + t]; s2 += red2[g * 128 + t]; }
            atomicAdd(&bnacc[t], s1);
            atomicAdd(&bnacc[128 + t], s2);
        }
    }
}

// ---------------- BN finalize + apply (in place) ----------------
__global__ void k_bnfinal(const float* __restrict__ bnacc, const float* __restrict__ gamma,
                          const float* __restrict__ beta, float* __restrict__ bnsc) {
    int d = threadIdx.x;
    if (d < DIM) {
        float mu = bnacc[d] / (float)N_NODES;
        float var = bnacc[128 + d] / (float)N_NODES - mu * mu;
        float rstd = rsqrtf(var + BN_EPS);
        float sc = gamma[d] * rstd;
        bnsc[d] = sc;
        bnsc[128 + d] = beta[d] - mu * sc;
    }
}

__global__ void k_bnapply(float* __restrict__ H, const float* __restrict__ bnsc) {
    int i4 = blockIdx.x * 256 + threadIdx.x;  // float4 index
    if (i4 < N_NODES * DIM / 4) {
        int d0 = (i4 * 4) & (DIM - 1);
        float4 v = *reinterpret_cast<float4*>(&H[(size_t)i4 * 4]);
        float4 sc = *reinterpret_cast<const float4*>(&bnsc[d0]);
        float4 sh = *reinterpret_cast<const float4*>(&bnsc[128 + d0]);
        v.x = fmaxf(v.x * sc.x + sh.x, 0.f);
        v.y = fmaxf(v.y * sc.y + sh.y, 0.f);
        v.z = fmaxf(v.z * sc.z + sh.z, 0.f);
        v.w = fmaxf(v.w * sc.w + sh.w, 0.f);
        *reinterpret_cast<float4*>(&H[(size_t)i4 * 4]) = v;
    }
}

// ---------------- graph mean pool (batch is sorted) ----------------
__global__ void k_pool(const float* __restrict__ H1, const int* __restrict__ batch,
                       float* __restrict__ gout) {
    int g = blockIdx.x;
    int d = threadIdx.x;  // 128 threads
    int lo = 0, hi = N_NODES;
    while (lo < hi) { int m = (lo + hi) >> 1; if (batch[m] < g) lo = m + 1; else hi = m; }
    int s = lo;
    lo = 0; hi = N_NODES;
    while (lo < hi) { int m = (lo + hi) >> 1; if (batch[m] < g + 1) lo = m + 1; else hi = m; }
    int e = lo;
    float sum = 0.f;
    for (int n = s; n < e; ++n) sum += H1[(size_t)n * DIM + d];
    gout[g * DIM + d] = sum / (float)max(e - s, 1);
}

// ---------------- projection: OUT = relu(H1) @ Wp^T + bp ----------------
__global__ __launch_bounds__(256) void k_proj(const float* __restrict__ H1,
                                              const float* __restrict__ Wp,
                                              const float* __restrict__ bp,
                                              float* __restrict__ OUT) {
    __shared__ float As[64][36];
    __shared__ float Ws[64][36];
    int t = threadIdx.x;
    int n0 = blockIdx.x * 64;
    int tn = t >> 4;  // 0..15
    int tc = t & 15;  // 0..15, c = tc + 16*j
    float acc[4][4];
#pragma unroll
    for (int i = 0; i < 4; ++i)
#pragma unroll
        for (int j = 0; j < 4; ++j) acc[i][j] = 0.f;
    int lr = t >> 3;
    int lc = (t & 7) * 4;
    for (int kc = 0; kc < 4; ++kc) {
        int kb = kc * 32;
        __syncthreads();
#pragma unroll
        for (int h = 0; h < 2; ++h) {
            int r = lr + h * 32;
            int n = n0 + r; if (n > N_NODES - 1) n = N_NODES - 1;
            float4 v = *reinterpret_cast<const float4*>(&H1[(size_t)n * DIM + kb + lc]);
            v.x = fmaxf(v.x, 0.f); v.y = fmaxf(v.y, 0.f);
            v.z = fmaxf(v.z, 0.f); v.w = fmaxf(v.w, 0.f);
            *reinterpret_cast<float4*>(&As[r][lc]) = v;
            *reinterpret_cast<float4*>(&Ws[r][lc]) =
                *reinterpret_cast<const float4*>(&Wp[(size_t)r * DIM + kb + lc]);
        }
        __syncthreads();
#pragma unroll
        for (int kk = 0; kk < 8; ++kk) {
            float4 a[4], w[4];
#pragma unroll
            for (int i = 0; i < 4; ++i)
                a[i] = *reinterpret_cast<const float4*>(&As[tn * 4 + i][kk * 4]);
#pragma unroll
            for (int j = 0; j < 4; ++j)
                w[j] = *reinterpret_cast<const float4*>(&Ws[tc + 16 * j][kk * 4]);
#pragma unroll
            for (int i = 0; i < 4; ++i)
#pragma unroll
                for (int j = 0; j < 4; ++j)
                    acc[i][j] += a[i].x * w[j].x + a[i].y * w[j].y
                               + a[i].z * w[j].z + a[i].w * w[j].w;
        }
    }
    float bj[4];
#pragma unroll
    for (int j = 0; j < 4; ++j) bj[j] = bp[tc + 16 * j];
#pragma unroll
    for (int i = 0; i < 4; ++i) {
        int n = n0 + tn * 4 + i;
        if (n < N_NODES) {
#pragma unroll
            for (int j = 0; j < 4; ++j)
                OUT[(size_t)n * NCLS + tc + 16 * j] = acc[i][j] + bj[j];
        }
    }
}

extern "C" void kernel_launch(void* const* d_in, const int* in_sizes, int n_in,
                              void* d_out, int out_size, void* d_ws, size_t ws_size,
                              hipStream_t stream) {
    (void)in_sizes; (void)n_in; (void)out_size; (void)ws_size;
    const float* x     = (const float*)d_in[0];
    const float* xe    = (const float*)d_in[1];
    const int*   eidx  = (const int*)d_in[2];
    const int*   batch = (const int*)d_in[3];
    const float* Wl0   = (const float*)d_in[4];
    const float* bl0   = (const float*)d_in[5];
    const float* Wr0   = (const float*)d_in[6];
    const float* Wl1   = (const float*)d_in[7];
    const float* bl1   = (const float*)d_in[8];
    const float* Wr1   = (const float*)d_in[9];
    const float* gamma0 = (const float*)d_in[10];
    const float* beta0  = (const float*)d_in[11];
    const float* Wp    = (const float*)d_in[12];
    const float* bp    = (const float*)d_in[13];
    const int* srcp = eidx;
    const int* dstp = eidx + N_EDGES;

    char* ws = (char*)d_ws;
    size_t off = 0;
    auto carve = [&](size_t bytes) {
        void* p = ws + off;
        off = (off + bytes + 255) & ~(size_t)255;
        return p;
    };
    int*   cnt    = (int*)carve((size_t)N_NODES * 4);
    int*   rowptr = (int*)carve((size_t)(N_NODES + 1) * 4);
    int*   wcur   = (int*)carve((size_t)N_NODES * 4);
    int*   bsums  = (int*)carve(128 * 4);
    float* bnacc  = (float*)carve(256 * 4);
    float* bnsc   = (float*)carve(256 * 4);
    int2*  esort  = (int2*)carve((size_t)N_EDGES * 8);
    float* AGG    = (float*)carve((size_t)N_NODES * DIM * 4);
    float* H      = (float*)carve((size_t)N_NODES * DIM * 4);
    float* H1     = (float*)carve((size_t)N_NODES * DIM * 4);

    float* out_h = (float*)d_out;
    float* out_g = out_h + (size_t)N_NODES * NCLS;

    hipMemsetAsync(cnt, 0, (size_t)N_NODES * 4, stream);
    hipMemsetAsync(bnacc, 0, 256 * 4, stream);

    int nb = (N_NODES + 1023) / 1024;  // 98
    k_hist<<<(N_EDGES + 255) / 256, 256, 0, stream>>>(dstp, cnt);
    k_scan1<<<nb, 1024, 0, stream>>>(cnt, rowptr, bsums);
    k_scan2<<<1, 64, 0, stream>>>(bsums, nb);
    k_scan3<<<nb, 1024, 0, stream>>>(rowptr, bsums, wcur);
    k_scatter<<<(N_EDGES + 255) / 256, 256, 0, stream>>>(srcp, dstp, wcur, esort);

    // layer 0
    k_agg<<<(N_NODES * 64 + 255) / 256, 256, 0, stream>>>(x, xe, rowptr, esort, AGG);
    k_gemm2<<<(N_NODES + 63) / 64, 256, 0, stream>>>(AGG, x, Wl0, Wr0, bl0, H, bnacc, 1);
    k_bnfinal<<<1, 128, 0, stream>>>(bnacc, gamma0, beta0, bnsc);
    k_bnapply<<<(N_NODES * DIM / 4 + 255) / 256, 256, 0, stream>>>(H, bnsc);

    // layer 1
    k_agg<<<(N_NODES * 64 + 255) / 256, 256, 0, stream>>>(H, xe, rowptr, esort, AGG);
    k_gemm2<<<(N_NODES + 63) / 64, 256, 0, stream>>>(AGG, H, Wl1, Wr1, bl1, H1, bnacc, 0);

    // readout
    k_pool<<<NG, 128, 0, stream>>>(H1, batch, out_g);
    k_proj<<<(N_NODES + 63) / 64, 256, 0, stream>>>(H1, Wp, bp, out_h);
}